// Round 4
// baseline (1083.615 us; speedup 1.0000x reference)
//
#include <hip/hip_runtime.h>
#include <hip/hip_bf16.h>

// ECLGCNN: ChebConv(K=3) on 49152 disjoint 32-node graphs -> per-sample BN ->
// sigmoid -> LSTM(48 steps, H=512) -> linear head. Inputs fp32, output fp32.
// R11: revert k_lstm sync to R9-proven form (402us): padded counter + RELAXED
// fetch_add release, 1-lane poll + s_sleep(4), per-lane 2B write-through h
// stores. R10's 64-lane poll was fetch-amplifying (FETCH 312->980MB, L2-
// uncacheable atomic loads on a 128B line at 2x poll rate) and the 8B atomic
// store epilogue RAISED WRITE_SIZE. Keep R10's k_graph full-wave phases,
// k_stats elimination, bn_acc-zero fusion. Poll sits after X-MFMA (overlap).

#define B_    1024
#define T_    48
#define NPG_  32
#define F_    5
#define H_    512
#define EPG_  256
#define NG_   (B_*T_)          // 49152 graphs
#define N_    (B_*T_*NPG_)     // 1572864 nodes
#define E_    (B_*T_*EPG_)     // 12582912 edges
#define NF_   (N_*F_)          // 7864320

typedef __bf16 bf16x8 __attribute__((ext_vector_type(8)));
typedef float  f32x4  __attribute__((ext_vector_type(4)));
typedef __hip_bfloat16 bf16;

__device__ __forceinline__ float sigm(float x)   { return 1.0f/(1.0f+__expf(-x)); }
__device__ __forceinline__ float tanh_f(float x) { return 2.0f/(1.0f+__expf(-2.0f*x)) - 1.0f; }

__device__ __forceinline__ void gl_lds16(const void* g, void* l) {
    __builtin_amdgcn_global_load_lds((const __attribute__((address_space(1))) unsigned int*)g,
                                     (__attribute__((address_space(3))) unsigned int*)l, 16, 0, 0);
}

// write-through bf16 store: coherent at agent scope (MALL), no local-L2 dirty line
__device__ __forceinline__ void store_h_wt(bf16* p, float v) {
    bf16 b = __float2bfloat16(v);
    unsigned short us; __builtin_memcpy(&us, &b, 2);
    __hip_atomic_store(reinterpret_cast<unsigned short*>(p), us,
                       __ATOMIC_RELAXED, __HIP_MEMORY_SCOPE_AGENT);
}

__global__ __launch_bounds__(256) void k_zero(float4* p, int n) {
    int i = blockIdx.x*256 + threadIdx.x;
    if (i < n) p[i] = make_float4(0.f, 0.f, 0.f, 0.f);
}

// Pack W' = [Wih | Whh] row-major [2048][672], fp32 -> bf16. Blocks 0-9 also
// zero bn_acc (k_graph atomic-accumulates BN partials into it).
__global__ __launch_bounds__(256) void k_pack(const float* __restrict__ Wih,
                                              const float* __restrict__ Whh,
                                              bf16* __restrict__ Wp,
                                              float* __restrict__ bn_acc) {
    int i = blockIdx.x*256 + threadIdx.x;           // < 2048*672
    if (blockIdx.x < 10) bn_acc[blockIdx.x*256 + threadIdx.x] = 0.f;
    int r = i / 672, c = i - r*672;
    float v = (c < 160) ? Wih[r*160 + c] : Whh[r*512 + (c-160)];
    Wp[i] = __float2bfloat16(v);
}

// Graph-per-wave ChebConv: 4 graphs per 256-thread block.
__global__ __launch_bounds__(256) void k_graph(
    const float* __restrict__ x, const float* __restrict__ ea,
    const float* __restrict__ cW, const float* __restrict__ cb,
    const int* __restrict__ ei, float* __restrict__ y_pre,
    float* __restrict__ bn_acc)
{
    const int tid = threadIdx.x, w = tid >> 6, lane = tid & 63;
    const int g = blockIdx.x*4 + w;
    __shared__ float Msh[4][1056];                  // Mt[d][s], row stride 33
    __shared__ float dinv[4][32];
    __shared__ float T0s[4][160], T1s[4][160], T2s[4][160];
    __shared__ __align__(16) float Spad[4][256];    // scaled vec, rows padded to 8
    __shared__ float Wsh[75], bsh[5];
    float* mt = Msh[w];

    if (lane < 75) Wsh[lane] = cW[lane];
    if (lane < 5)  bsh[lane] = cb[lane];
    const float4 ew = *reinterpret_cast<const float4*>(ea + (size_t)g*256 + lane*4);
    const int4   es = *reinterpret_cast<const int4*>(ei + (size_t)g*256 + lane*4);
    const int4   ed = *reinterpret_cast<const int4*>(ei + (size_t)E_ + (size_t)g*256 + lane*4);
    T0s[w][lane]      = x[(size_t)g*160 + lane];
    T0s[w][64+lane]   = x[(size_t)g*160 + 64 + lane];
    if (lane < 32) T0s[w][128+lane] = x[(size_t)g*160 + 128 + lane];
    for (int i = lane; i < 1056; i += 64) mt[i] = 0.f;
    __syncthreads();
    atomicAdd(&mt[(ed.x & 31)*33 + (es.x & 31)], ew.x);
    atomicAdd(&mt[(ed.y & 31)*33 + (es.y & 31)], ew.y);
    atomicAdd(&mt[(ed.z & 31)*33 + (es.z & 31)], ew.z);
    atomicAdd(&mt[(ed.w & 31)*33 + (es.w & 31)], ew.w);
    __syncthreads();
    {                                               // deg[s] = sum_d Mt[d][s], 64-lane
        const int s = lane & 31, hh = lane >> 5;
        float dg = 0.f;
        #pragma unroll
        for (int k = 0; k < 16; ++k) dg += mt[(hh*16 + k)*33 + s];
        dg += __shfl_xor(dg, 32, 64);
        if (lane < 32) dinv[w][lane] = dg > 0.f ? rsqrtf(dg) : 0.f;
    }
    __syncthreads();
    for (int i = lane; i < 160; i += 64) Spad[w][(i/5)*8 + (i%5)] = dinv[w][i/5]*T0s[w][i];
    __syncthreads();
    {                                               // T1 = -dinv .* (Mt @ S0), 64-lane
        const int d = lane & 31, hh = lane >> 5;
        float a0=0.f,a1=0.f,a2=0.f,a3=0.f,a4=0.f;
        #pragma unroll 4
        for (int s2 = 0; s2 < 16; ++s2) {
            const int s = s2*2 + hh;
            const float m = mt[d*33+s];
            const float4 sv = *reinterpret_cast<const float4*>(&Spad[w][s*8]);
            const float s4 = Spad[w][s*8+4];
            a0 += m*sv.x; a1 += m*sv.y; a2 += m*sv.z; a3 += m*sv.w; a4 += m*s4;
        }
        a0 += __shfl_xor(a0, 32, 64); a1 += __shfl_xor(a1, 32, 64);
        a2 += __shfl_xor(a2, 32, 64); a3 += __shfl_xor(a3, 32, 64);
        a4 += __shfl_xor(a4, 32, 64);
        if (lane < 32) {
            const float sc = -dinv[w][d];
            T1s[w][d*5+0]=sc*a0; T1s[w][d*5+1]=sc*a1; T1s[w][d*5+2]=sc*a2;
            T1s[w][d*5+3]=sc*a3; T1s[w][d*5+4]=sc*a4;
        }
    }
    __syncthreads();
    for (int i = lane; i < 160; i += 64) Spad[w][(i/5)*8 + (i%5)] = dinv[w][i/5]*T1s[w][i];
    __syncthreads();
    {                                               // T2 = 2 L~ T1 - T0, 64-lane
        const int d = lane & 31, hh = lane >> 5;
        float a0=0.f,a1=0.f,a2=0.f,a3=0.f,a4=0.f;
        #pragma unroll 4
        for (int s2 = 0; s2 < 16; ++s2) {
            const int s = s2*2 + hh;
            const float m = mt[d*33+s];
            const float4 sv = *reinterpret_cast<const float4*>(&Spad[w][s*8]);
            const float s4 = Spad[w][s*8+4];
            a0 += m*sv.x; a1 += m*sv.y; a2 += m*sv.z; a3 += m*sv.w; a4 += m*s4;
        }
        a0 += __shfl_xor(a0, 32, 64); a1 += __shfl_xor(a1, 32, 64);
        a2 += __shfl_xor(a2, 32, 64); a3 += __shfl_xor(a3, 32, 64);
        a4 += __shfl_xor(a4, 32, 64);
        if (lane < 32) {
            const float sc = -2.f*dinv[w][d];
            T2s[w][d*5+0]=sc*a0-T0s[w][d*5+0]; T2s[w][d*5+1]=sc*a1-T0s[w][d*5+1];
            T2s[w][d*5+2]=sc*a2-T0s[w][d*5+2]; T2s[w][d*5+3]=sc*a3-T0s[w][d*5+3];
            T2s[w][d*5+4]=sc*a4-T0s[w][d*5+4];
        }
    }
    __syncthreads();
    float* vb = mt;                                 // reuse adjacency LDS for y
    for (int i = lane; i < 160; i += 64) {
        const int n = i/5, f = i - 5*n;
        float v = bsh[f];
        #pragma unroll
        for (int c = 0; c < 5; ++c)
            v += T0s[w][n*5+c]*Wsh[c*5+f] + T1s[w][n*5+c]*Wsh[25+c*5+f] + T2s[w][n*5+c]*Wsh[50+c*5+f];
        y_pre[(size_t)g*160 + i] = v;
        vb[i] = v;
    }
    __syncthreads();
    {                                               // BN partials -> bn_acc (atomic)
        const int f = lane % 5, cs = (lane/5) & 3;
        const bool sq = lane >= 20;
        float sm = 0.f;
        if (lane < 40) {
            #pragma unroll
            for (int k = 0; k < 8; ++k) { float v = vb[(cs*8+k)*5+f]; sm += sq ? v*v : v; }
        }
        sm += __shfl_down(sm, 5, 64);
        sm += __shfl_down(sm, 10, 64);
        if (lane < 40 && cs == 0)
            atomicAdd(&bn_acc[(size_t)(g/T_)*10 + f + (sq?5:0)], sm);
    }
}

__global__ __launch_bounds__(256) void k_bn(
    const float* __restrict__ y_pre, const float* __restrict__ bn_acc,
    const float* __restrict__ gamma, const float* __restrict__ beta,
    bf16* __restrict__ X)
{
    const int i = blockIdx.x*256 + threadIdx.x;
    const int b   = i / 7680;
    const int rem = i - b*7680;
    const int t   = rem / 160;
    const int pf  = rem - t*160;
    const int f   = pf % 5;
    const float inv  = 1.0f/1536.0f;
    const float mean = bn_acc[b*10+f]*inv;
    const float var  = bn_acc[b*10+5+f]*inv - mean*mean;
    const float v = gamma[f]*(y_pre[i]-mean)*rsqrtf(var+1e-5f) + beta[f];
    X[((size_t)t*B_ + b)*160 + pf] = __float2bfloat16(sigm(v));
}

// ---- persistent LSTM: 3-phase staged GEMM per step, flag-sync between steps ----
// R9-proven sync: h in fresh slabs h_all[t], written WRITE-THROUGH (per-lane 2B
// agent-relaxed atomic stores). One 128B-padded counter per (t,mi); producers
// RELAXED fetch_add after vmcnt drain; 1-lane consumer poll + s_sleep(4),
// placed after the X-part MFMA so the whole h-independent phase overlaps it.
// c_buf is block-private (same block owns the same tile every step).

__device__ __forceinline__ void stage_A(const char* gbase, int strideB, char* lds,
                                        int gpr, int xmask, int nper, int tid) {
    for (int p = 0; p < nper; ++p) {
        const int S = p*256 + tid;
        const int row = S / gpr;
        const int col = (S - row*gpr) ^ (row & xmask);
        gl_lds16(gbase + (size_t)row*strideB + (size_t)col*16, lds + (size_t)S*16);
    }
}

__device__ __forceinline__ void stage_W(const char* Wbase, char* lds,
                                        int gpr, int xmask, int nper, int tid, int u0) {
    for (int p = 0; p < nper; ++p) {
        const int S = p*256 + tid;
        const int row = S / gpr;
        const int col = (S - row*gpr) ^ (row & xmask);
        const int wrow = ((row >> 4) << 9) + u0 + (row & 15);
        gl_lds16(Wbase + (size_t)wrow*1344 + (size_t)col*16, lds + (size_t)S*16);
    }
}

__device__ __forceinline__ void mfma_phase(const char* Al, const char* Wl, int gpr,
                                           int xmask, int nkk, int arow, int lo,
                                           int quad, f32x4 acc[4]) {
    for (int kk = 0; kk < nkk; ++kk) {
        const int kq = kk*4 + quad;
        const bf16x8 a = *reinterpret_cast<const bf16x8*>(
            Al + ((size_t)arow*gpr + (kq ^ (arow & xmask)))*16);
        #pragma unroll
        for (int g = 0; g < 4; ++g) {
            const int wr = g*16 + lo;
            const bf16x8 b = *reinterpret_cast<const bf16x8*>(
                Wl + ((size_t)wr*gpr + (kq ^ (wr & xmask)))*16);
            acc[g] = __builtin_amdgcn_mfma_f32_16x16x32_bf16(a, b, acc[g], 0, 0, 0);
        }
    }
}

__global__ __launch_bounds__(256, 2) void k_lstm(
    const bf16* __restrict__ X,  const bf16* __restrict__ Wp,
    const float* __restrict__ bih, const float* __restrict__ bhh,
    bf16* __restrict__ h_all, float* __restrict__ c_buf,
    int* __restrict__ cnt)
{
    extern __shared__ char sm[];
    char* Al = sm;
    char* Wl = sm + 32768;
    const int tid = threadIdx.x;
    const int lane = tid & 63, w = tid >> 6;
    const int lo = lane & 15, quad = lane >> 4;
    const int arow = w*16 + lo;
    const char* Wb = (const char*)Wp;

    for (int t = 0; t < T_; ++t) {
        const char* Hin = (const char*)(h_all + (size_t)t*B_*H_);
        bf16* h_out = h_all + (size_t)(t+1)*B_*H_;
        for (int tile = blockIdx.x; tile < 512; tile += gridDim.x) {
            const int mi = tile >> 5, ui = tile & 31;
            const int m0 = mi*64, u0 = ui*16;
            const char* Xb = (const char*)X + (size_t)t*B_*320 + (size_t)m0*320;
            const char* Hb = Hin + (size_t)m0*1024;
            f32x4 acc[4] = {};

            // phase 0: X part (K=160) -- h-independent; overlaps the wait
            stage_A(Xb, 320, Al, 20, 3, 5, tid);
            stage_W(Wb, Wl, 20, 3, 5, tid, u0);
            const int u = u0 + lo;
            const float bI = bih[u]      + bhh[u];
            const float bF = bih[512+u]  + bhh[512+u];
            const float bG = bih[1024+u] + bhh[1024+u];
            const float bO = bih[1536+u] + bhh[1536+u];
            __syncthreads();                          // drains vmcnt: LDS ready
            mfma_phase(Al, Wl, 20, 3, 5, arow, lo, quad, acc);
            if (t > 0 && tid == 0) {                  // wait h producers of step t-1
                int* p = cnt + (size_t)((t-1)*16 + mi)*32;
                while (__hip_atomic_load(p, __ATOMIC_RELAXED, __HIP_MEMORY_SCOPE_AGENT) < 32)
                    __builtin_amdgcn_s_sleep(4);
            }
            __syncthreads();
            // phase 1: h[0:256)
            stage_A(Hb, 1024, Al, 32, 7, 8, tid);
            stage_W(Wb + 320, Wl, 32, 7, 8, tid, u0);
            __syncthreads();
            mfma_phase(Al, Wl, 32, 7, 8, arow, lo, quad, acc);
            __syncthreads();
            // phase 2: h[256:512)
            stage_A(Hb + 512, 1024, Al, 32, 7, 8, tid);
            stage_W(Wb + 832, Wl, 32, 7, 8, tid, u0);
            __syncthreads();
            mfma_phase(Al, Wl, 32, 7, 8, arow, lo, quad, acc);

            #pragma unroll
            for (int r = 0; r < 4; ++r) {
                const int m = m0 + w*16 + quad*4 + r;
                const int idx = m*512 + u;
                const float iv = acc[0][r] + bI;
                const float fv = acc[1][r] + bF;
                const float gv = acc[2][r] + bG;
                const float ov = acc[3][r] + bO;
                const float c_new = sigm(fv)*c_buf[idx] + sigm(iv)*tanh_f(gv);
                c_buf[idx] = c_new;
                store_h_wt(&h_out[idx], sigm(ov)*tanh_f(c_new));
            }
            __syncthreads();                          // drains vmcnt: h at MALL
            if (tid == 0)                             // relaxed: no L2 writeback
                __hip_atomic_fetch_add(cnt + (size_t)(t*16 + mi)*32, 1,
                                       __ATOMIC_RELAXED, __HIP_MEMORY_SCOPE_AGENT);
        }
    }
}

// out[b,j] = sigmoid( sum_{t,u} sigm(h[t,b,u]) * lin_W[j, t*512+u] + lin_b[j] )
__global__ __launch_bounds__(256) void k_final(
    const bf16* __restrict__ hs, const float* __restrict__ lW,
    const float* __restrict__ lb, float* __restrict__ out)
{
    const int b = blockIdx.x, tid = threadIdx.x;
    const int u = tid*2;
    float a0=0.f, a1=0.f, a2=0.f, a3=0.f;
    for (int t = 0; t < T_; ++t) {
        const bf16* hr = hs + ((size_t)t*B_ + b)*H_ + u;
        const float h0 = sigm((float)hr[0]), h1 = sigm((float)hr[1]);
        const int o = t*H_ + u;
        a0 += h0*lW[o]         + h1*lW[o+1];
        a1 += h0*lW[24576+o]   + h1*lW[24576+o+1];
        a2 += h0*lW[49152+o]   + h1*lW[49152+o+1];
        a3 += h0*lW[73728+o]   + h1*lW[73728+o+1];
    }
    #pragma unroll
    for (int off = 32; off > 0; off >>= 1) {
        a0 += __shfl_down(a0, off, 64);
        a1 += __shfl_down(a1, off, 64);
        a2 += __shfl_down(a2, off, 64);
        a3 += __shfl_down(a3, off, 64);
    }
    __shared__ float red[4][4];
    const int wave = tid >> 6, lane = tid & 63;
    if (lane == 0) { red[0][wave]=a0; red[1][wave]=a1; red[2][wave]=a2; red[3][wave]=a3; }
    __syncthreads();
    if (tid < 4) {
        float s = red[tid][0]+red[tid][1]+red[tid][2]+red[tid][3] + lb[tid];
        out[b*4 + tid] = sigm(s);
    }
}

extern "C" void kernel_launch(void* const* d_in, const int* in_sizes, int n_in,
                              void* d_out, int out_size, void* d_ws, size_t ws_size,
                              hipStream_t stream) {
    const float* x   = (const float*)d_in[0];
    const float* ea  = (const float*)d_in[1];
    const float* cW  = (const float*)d_in[2];
    const float* cb  = (const float*)d_in[3];
    const float* gam = (const float*)d_in[4];
    const float* bet = (const float*)d_in[5];
    const float* Wih = (const float*)d_in[6];
    const float* Whh = (const float*)d_in[7];
    const float* bih = (const float*)d_in[8];
    const float* bhh = (const float*)d_in[9];
    const float* lW  = (const float*)d_in[10];
    const float* lb  = (const float*)d_in[11];
    const int*   ei  = (const int*)d_in[12];
    float* out = (float*)d_out;

    // Workspace (~69 MB):
    // [bn_acc 40KB][Wp 2.75MB][X 15.7MB][big 51.2MB]
    // big phase 1: y_pre @0 (31.5MB)
    // big phase 2: cnt @0 (128KB, one 128B counter line per (t,mi)),
    //              c @128KB (2MB), h_all @128KB+2MB (49 x 1MB)
    char* ws = (char*)d_ws;
    float* bn_acc = (float*)ws;
    bf16*  Wp     = (bf16*)(ws + 40960);
    bf16*  X      = (bf16*)(ws + 2793472);
    char*  big    = ws + 18522112;
    float* y_pre  = (float*)big;
    int*   cnt    = (int*)big;
    float* c_buf  = (float*)(big + 131072);
    bf16*  h_all  = (bf16*)(big + 131072 + 2097152);

    (void)hipFuncSetAttribute((const void*)k_lstm,
                              hipFuncAttributeMaxDynamicSharedMemorySize, 65536);

    static int nblk = 0;                 // persistent grid: 2 blocks/CU resident
    if (nblk == 0) {
        int dev = 0, ncu = 0;
        if (hipGetDevice(&dev) != hipSuccess) dev = 0;
        if (hipDeviceGetAttribute(&ncu, hipDeviceAttributeMultiprocessorCount, dev)
                != hipSuccess || ncu <= 0) ncu = 256;
        nblk = 2*ncu; if (nblk > 512) nblk = 512;
    }

    k_pack<<<5376, 256, 0, stream>>>(Wih, Whh, Wp, bn_acc);
    k_graph<<<NG_/4, 256, 0, stream>>>(x, ea, cW, cb, ei, y_pre, bn_acc);
    k_bn<<<NF_/256, 256, 0, stream>>>(y_pre, bn_acc, gam, bet, X);
    // zero cnt (128KB) + c (2MB) + h_all slab 0 (1MB) = 204800 float4
    k_zero<<<800, 256, 0, stream>>>((float4*)big, 204800);
    k_lstm<<<nblk, 256, 65536, stream>>>(X, Wp, bih, bhh, h_all, c_buf, cnt);
    k_final<<<B_, 256, 0, stream>>>(h_all + (size_t)B_*H_, lW, lb, out);
}

// Round 6
// 727.301 us; speedup vs baseline: 1.4899x; 1.4899x over previous
//
#include <hip/hip_runtime.h>
#include <hip/hip_bf16.h>

// ECLGCNN: ChebConv(K=3) on 49152 disjoint 32-node graphs -> per-sample BN ->
// sigmoid -> LSTM(48 steps, H=512) -> linear head. Inputs fp32, output fp32.
// R13: R12's W-resident LSTM with LDS cut 148KB -> 128KB (gfx950-proven cap;
// R12's 151552B dynamic-LDS launch silently failed -> NaN from unwritten h).
// W1/W2 (h-part weights, 64KB) resident across all 48 steps; X (40KB) + W0
// (20KB, L2-resident slice) staged per step into the 64KB A-buffer.
// 256 blocks x 512 thr (8 waves), tile 128m x 64 gate-rows, 1 block/CU.
// Sync = R9-proven protocol (padded cnt, relaxed fetch_add after vmcnt drain,
// 1-lane poll + s_sleep(4) before first barrier, 2B WT h stores, fresh slabs).

#define B_    1024
#define T_    48
#define NPG_  32
#define F_    5
#define H_    512
#define EPG_  256
#define NG_   (B_*T_)          // 49152 graphs
#define N_    (B_*T_*NPG_)     // 1572864 nodes
#define E_    (B_*T_*EPG_)     // 12582912 edges
#define NF_   (N_*F_)          // 7864320

typedef __bf16 bf16x8 __attribute__((ext_vector_type(8)));
typedef float  f32x4  __attribute__((ext_vector_type(4)));
typedef __hip_bfloat16 bf16;

__device__ __forceinline__ float sigm(float x)   { return 1.0f/(1.0f+__expf(-x)); }
__device__ __forceinline__ float tanh_f(float x) { return 2.0f/(1.0f+__expf(-2.0f*x)) - 1.0f; }

__device__ __forceinline__ void gl_lds16(const void* g, void* l) {
    __builtin_amdgcn_global_load_lds((const __attribute__((address_space(1))) unsigned int*)g,
                                     (__attribute__((address_space(3))) unsigned int*)l, 16, 0, 0);
}

// write-through bf16 store: coherent at agent scope (MALL), no local-L2 dirty line
__device__ __forceinline__ void store_h_wt(bf16* p, float v) {
    bf16 b = __float2bfloat16(v);
    unsigned short us; __builtin_memcpy(&us, &b, 2);
    __hip_atomic_store(reinterpret_cast<unsigned short*>(p), us,
                       __ATOMIC_RELAXED, __HIP_MEMORY_SCOPE_AGENT);
}

__global__ __launch_bounds__(256) void k_zero(float4* p, int n) {
    int i = blockIdx.x*256 + threadIdx.x;
    if (i < n) p[i] = make_float4(0.f, 0.f, 0.f, 0.f);
}

// Pack W' = [Wih | Whh] row-major [2048][672], fp32 -> bf16. Blocks 0-9 also
// zero bn_acc (k_graph atomic-accumulates BN partials into it).
__global__ __launch_bounds__(256) void k_pack(const float* __restrict__ Wih,
                                              const float* __restrict__ Whh,
                                              bf16* __restrict__ Wp,
                                              float* __restrict__ bn_acc) {
    int i = blockIdx.x*256 + threadIdx.x;           // < 2048*672
    if (blockIdx.x < 10) bn_acc[blockIdx.x*256 + threadIdx.x] = 0.f;
    int r = i / 672, c = i - r*672;
    float v = (c < 160) ? Wih[r*160 + c] : Whh[r*512 + (c-160)];
    Wp[i] = __float2bfloat16(v);
}

// Graph-per-wave ChebConv: 4 graphs per 256-thread block.
__global__ __launch_bounds__(256) void k_graph(
    const float* __restrict__ x, const float* __restrict__ ea,
    const float* __restrict__ cW, const float* __restrict__ cb,
    const int* __restrict__ ei, float* __restrict__ y_pre,
    float* __restrict__ bn_acc)
{
    const int tid = threadIdx.x, w = tid >> 6, lane = tid & 63;
    const int g = blockIdx.x*4 + w;
    __shared__ float Msh[4][1056];                  // Mt[d][s], row stride 33
    __shared__ float dinv[4][32];
    __shared__ float T0s[4][160], T1s[4][160], T2s[4][160];
    __shared__ __align__(16) float Spad[4][256];    // scaled vec, rows padded to 8
    __shared__ float Wsh[75], bsh[5];
    float* mt = Msh[w];

    if (lane < 75) Wsh[lane] = cW[lane];
    if (lane < 5)  bsh[lane] = cb[lane];
    const float4 ew = *reinterpret_cast<const float4*>(ea + (size_t)g*256 + lane*4);
    const int4   es = *reinterpret_cast<const int4*>(ei + (size_t)g*256 + lane*4);
    const int4   ed = *reinterpret_cast<const int4*>(ei + (size_t)E_ + (size_t)g*256 + lane*4);
    T0s[w][lane]      = x[(size_t)g*160 + lane];
    T0s[w][64+lane]   = x[(size_t)g*160 + 64 + lane];
    if (lane < 32) T0s[w][128+lane] = x[(size_t)g*160 + 128 + lane];
    for (int i = lane; i < 1056; i += 64) mt[i] = 0.f;
    __syncthreads();
    atomicAdd(&mt[(ed.x & 31)*33 + (es.x & 31)], ew.x);
    atomicAdd(&mt[(ed.y & 31)*33 + (es.y & 31)], ew.y);
    atomicAdd(&mt[(ed.z & 31)*33 + (es.z & 31)], ew.z);
    atomicAdd(&mt[(ed.w & 31)*33 + (es.w & 31)], ew.w);
    __syncthreads();
    {                                               // deg[s] = sum_d Mt[d][s], 64-lane
        const int s = lane & 31, hh = lane >> 5;
        float dg = 0.f;
        #pragma unroll
        for (int k = 0; k < 16; ++k) dg += mt[(hh*16 + k)*33 + s];
        dg += __shfl_xor(dg, 32, 64);
        if (lane < 32) dinv[w][lane] = dg > 0.f ? rsqrtf(dg) : 0.f;
    }
    __syncthreads();
    for (int i = lane; i < 160; i += 64) Spad[w][(i/5)*8 + (i%5)] = dinv[w][i/5]*T0s[w][i];
    __syncthreads();
    {                                               // T1 = -dinv .* (Mt @ S0), 64-lane
        const int d = lane & 31, hh = lane >> 5;
        float a0=0.f,a1=0.f,a2=0.f,a3=0.f,a4=0.f;
        #pragma unroll 4
        for (int s2 = 0; s2 < 16; ++s2) {
            const int s = s2*2 + hh;
            const float m = mt[d*33+s];
            const float4 sv = *reinterpret_cast<const float4*>(&Spad[w][s*8]);
            const float s4 = Spad[w][s*8+4];
            a0 += m*sv.x; a1 += m*sv.y; a2 += m*sv.z; a3 += m*sv.w; a4 += m*s4;
        }
        a0 += __shfl_xor(a0, 32, 64); a1 += __shfl_xor(a1, 32, 64);
        a2 += __shfl_xor(a2, 32, 64); a3 += __shfl_xor(a3, 32, 64);
        a4 += __shfl_xor(a4, 32, 64);
        if (lane < 32) {
            const float sc = -dinv[w][d];
            T1s[w][d*5+0]=sc*a0; T1s[w][d*5+1]=sc*a1; T1s[w][d*5+2]=sc*a2;
            T1s[w][d*5+3]=sc*a3; T1s[w][d*5+4]=sc*a4;
        }
    }
    __syncthreads();
    for (int i = lane; i < 160; i += 64) Spad[w][(i/5)*8 + (i%5)] = dinv[w][i/5]*T1s[w][i];
    __syncthreads();
    {                                               // T2 = 2 L~ T1 - T0, 64-lane
        const int d = lane & 31, hh = lane >> 5;
        float a0=0.f,a1=0.f,a2=0.f,a3=0.f,a4=0.f;
        #pragma unroll 4
        for (int s2 = 0; s2 < 16; ++s2) {
            const int s = s2*2 + hh;
            const float m = mt[d*33+s];
            const float4 sv = *reinterpret_cast<const float4*>(&Spad[w][s*8]);
            const float s4 = Spad[w][s*8+4];
            a0 += m*sv.x; a1 += m*sv.y; a2 += m*sv.z; a3 += m*sv.w; a4 += m*s4;
        }
        a0 += __shfl_xor(a0, 32, 64); a1 += __shfl_xor(a1, 32, 64);
        a2 += __shfl_xor(a2, 32, 64); a3 += __shfl_xor(a3, 32, 64);
        a4 += __shfl_xor(a4, 32, 64);
        if (lane < 32) {
            const float sc = -2.f*dinv[w][d];
            T2s[w][d*5+0]=sc*a0-T0s[w][d*5+0]; T2s[w][d*5+1]=sc*a1-T0s[w][d*5+1];
            T2s[w][d*5+2]=sc*a2-T0s[w][d*5+2]; T2s[w][d*5+3]=sc*a3-T0s[w][d*5+3];
            T2s[w][d*5+4]=sc*a4-T0s[w][d*5+4];
        }
    }
    __syncthreads();
    float* vb = mt;                                 // reuse adjacency LDS for y
    for (int i = lane; i < 160; i += 64) {
        const int n = i/5, f = i - 5*n;
        float v = bsh[f];
        #pragma unroll
        for (int c = 0; c < 5; ++c)
            v += T0s[w][n*5+c]*Wsh[c*5+f] + T1s[w][n*5+c]*Wsh[25+c*5+f] + T2s[w][n*5+c]*Wsh[50+c*5+f];
        y_pre[(size_t)g*160 + i] = v;
        vb[i] = v;
    }
    __syncthreads();
    {                                               // BN partials -> bn_acc (atomic)
        const int f = lane % 5, cs = (lane/5) & 3;
        const bool sq = lane >= 20;
        float sm = 0.f;
        if (lane < 40) {
            #pragma unroll
            for (int k = 0; k < 8; ++k) { float v = vb[(cs*8+k)*5+f]; sm += sq ? v*v : v; }
        }
        sm += __shfl_down(sm, 5, 64);
        sm += __shfl_down(sm, 10, 64);
        if (lane < 40 && cs == 0)
            atomicAdd(&bn_acc[(size_t)(g/T_)*10 + f + (sq?5:0)], sm);
    }
}

__global__ __launch_bounds__(256) void k_bn(
    const float* __restrict__ y_pre, const float* __restrict__ bn_acc,
    const float* __restrict__ gamma, const float* __restrict__ beta,
    bf16* __restrict__ X)
{
    const int i = blockIdx.x*256 + threadIdx.x;
    const int b   = i / 7680;
    const int rem = i - b*7680;
    const int t   = rem / 160;
    const int pf  = rem - t*160;
    const int f   = pf % 5;
    const float inv  = 1.0f/1536.0f;
    const float mean = bn_acc[b*10+f]*inv;
    const float var  = bn_acc[b*10+5+f]*inv - mean*mean;
    const float v = gamma[f]*(y_pre[i]-mean)*rsqrtf(var+1e-5f) + beta[f];
    X[((size_t)t*B_ + b)*160 + pf] = __float2bfloat16(sigm(v));
}

// ---- W-resident persistent LSTM (128KB LDS) ----
// 256 tiles (8 m-groups x 32 u-tiles), tile = 128 batch rows x 64 gate rows
// (16u x 4 gates). 512-thread blocks (8 waves), 1 block/CU. LDS 131072:
//   A-buf 64KB  (P0: X 40KB + W0 20KB staged per step; P1/P2: h halves 64KB)
//   W1 32KB / W2 32KB -- staged ONCE before the t loop (h-part weights).
// Per step: P0 stage X+W0 + poll + barrier + mfma; P1/P2 stage h-half +
// barrier + mfma(W1/W2); epilogue c/h; barrier; flag. Sync = R9 protocol.

__device__ __forceinline__ void stage_A512(const char* gbase, int strideB, char* lds,
                                           int gpr, int xmask, int nper, int tid) {
    for (int p = 0; p < nper; ++p) {
        const int S = p*512 + tid;
        const int row = S / gpr;
        const int col = (S - row*gpr) ^ (row & xmask);
        gl_lds16(gbase + (size_t)row*strideB + (size_t)col*16, lds + (size_t)S*16);
    }
}

__device__ __forceinline__ void stage_W512(const char* Wbase, char* lds,
                                           int gpr, int xmask, int ntot, int tid, int u0) {
    for (int p = 0; p*512 < ntot; ++p) {
        const int S = p*512 + tid;
        if (S < ntot) {
            const int row = S / gpr;
            const int col = (S - row*gpr) ^ (row & xmask);
            const int wrow = ((row >> 4) << 9) + u0 + (row & 15);
            gl_lds16(Wbase + (size_t)wrow*1344 + (size_t)col*16, lds + (size_t)S*16);
        }
    }
}

__device__ __forceinline__ void mfma_phase(const char* Al, const char* Wl, int gpr,
                                           int xmask, int nkk, int arow, int lo,
                                           int quad, f32x4 acc[4]) {
    for (int kk = 0; kk < nkk; ++kk) {
        const int kq = kk*4 + quad;
        const bf16x8 a = *reinterpret_cast<const bf16x8*>(
            Al + ((size_t)arow*gpr + (kq ^ (arow & xmask)))*16);
        #pragma unroll
        for (int g = 0; g < 4; ++g) {
            const int wr = g*16 + lo;
            const bf16x8 b = *reinterpret_cast<const bf16x8*>(
                Wl + ((size_t)wr*gpr + (kq ^ (wr & xmask)))*16);
            acc[g] = __builtin_amdgcn_mfma_f32_16x16x32_bf16(a, b, acc[g], 0, 0, 0);
        }
    }
}

__global__ __launch_bounds__(512, 1) void k_lstm(
    const bf16* __restrict__ X,  const bf16* __restrict__ Wp,
    const float* __restrict__ bih, const float* __restrict__ bhh,
    bf16* __restrict__ h_all, float* __restrict__ c_buf,
    int* __restrict__ cnt)
{
    extern __shared__ char sm[];
    char* Al  = sm;                 // 65536 (P0: X@0 40960 + W0@40960 20480)
    char* W1l = sm + 65536;         // 32768
    char* W2l = sm + 98304;         // 32768
    const int tid = threadIdx.x;
    const int lane = tid & 63, w = tid >> 6;
    const int lo = lane & 15, quad = lane >> 4;
    const int arow = w*16 + lo;     // A row within 128-row tile
    const char* Wb = (const char*)Wp;
    const int ui = blockIdx.x & 31;
    const int u0 = ui*16;

    // stage resident W1/W2 once (depend only on ui, invariant per block)
    stage_W512(Wb + 320, W1l, 32, 7, 2048, tid, u0);
    stage_W512(Wb + 832, W2l, 32, 7, 2048, tid, u0);
    const int u = u0 + lo;
    const float bI = bih[u]      + bhh[u];
    const float bF = bih[512+u]  + bhh[512+u];
    const float bG = bih[1024+u] + bhh[1024+u];
    const float bO = bih[1536+u] + bhh[1536+u];

    for (int t = 0; t < T_; ++t) {
        const char* Hin = (const char*)(h_all + (size_t)t*B_*H_);
        bf16* h_out = h_all + (size_t)(t+1)*B_*H_;
        for (int tile = blockIdx.x; tile < 256; tile += gridDim.x) {
            const int mi = tile >> 5;
            const int m0 = mi*128;
            const char* Xb = (const char*)X + (size_t)t*B_*320 + (size_t)m0*320;
            const char* Hb = Hin + (size_t)m0*1024;
            f32x4 acc[4] = {};

            // phase 0: X part (K=160) -- h-independent; staging overlaps the poll
            stage_A512(Xb, 320, Al, 20, 3, 5, tid);          // X tile 40KB
            stage_W512(Wb, Al + 40960, 20, 3, 1280, tid, u0); // W0 20KB (L2-hot)
            if (t > 0 && tid == 0) {                  // wait h producers of step t-1
                int* p = cnt + (size_t)((t-1)*8 + mi)*32;
                while (__hip_atomic_load(p, __ATOMIC_RELAXED, __HIP_MEMORY_SCOPE_AGENT) < 32)
                    __builtin_amdgcn_s_sleep(4);
            }
            __syncthreads();                          // drains vmcnt: LDS ready
            mfma_phase(Al, Al + 40960, 20, 3, 5, arow, lo, quad, acc);
            __syncthreads();
            // phase 1: h[0:256)
            stage_A512(Hb, 1024, Al, 32, 7, 8, tid);
            __syncthreads();
            mfma_phase(Al, W1l, 32, 7, 8, arow, lo, quad, acc);
            __syncthreads();
            // phase 2: h[256:512)
            stage_A512(Hb + 512, 1024, Al, 32, 7, 8, tid);
            __syncthreads();
            mfma_phase(Al, W2l, 32, 7, 8, arow, lo, quad, acc);

            #pragma unroll
            for (int r = 0; r < 4; ++r) {
                const int m = m0 + w*16 + quad*4 + r;
                const int idx = m*512 + u;
                const float iv = acc[0][r] + bI;
                const float fv = acc[1][r] + bF;
                const float gv = acc[2][r] + bG;
                const float ov = acc[3][r] + bO;
                const float c_new = sigm(fv)*c_buf[idx] + sigm(iv)*tanh_f(gv);
                c_buf[idx] = c_new;
                store_h_wt(&h_out[idx], sigm(ov)*tanh_f(c_new));
            }
            __syncthreads();                          // drains vmcnt: h at MALL
            if (tid == 0)                             // relaxed: no L2 writeback
                __hip_atomic_fetch_add(cnt + (size_t)(t*8 + mi)*32, 1,
                                       __ATOMIC_RELAXED, __HIP_MEMORY_SCOPE_AGENT);
        }
    }
}

// out[b,j] = sigmoid( sum_{t,u} sigm(h[t,b,u]) * lin_W[j, t*512+u] + lin_b[j] )
__global__ __launch_bounds__(256) void k_final(
    const bf16* __restrict__ hs, const float* __restrict__ lW,
    const float* __restrict__ lb, float* __restrict__ out)
{
    const int b = blockIdx.x, tid = threadIdx.x;
    const int u = tid*2;
    float a0=0.f, a1=0.f, a2=0.f, a3=0.f;
    for (int t = 0; t < T_; ++t) {
        const bf16* hr = hs + ((size_t)t*B_ + b)*H_ + u;
        const float h0 = sigm((float)hr[0]), h1 = sigm((float)hr[1]);
        const int o = t*H_ + u;
        a0 += h0*lW[o]         + h1*lW[o+1];
        a1 += h0*lW[24576+o]   + h1*lW[24576+o+1];
        a2 += h0*lW[49152+o]   + h1*lW[49152+o+1];
        a3 += h0*lW[73728+o]   + h1*lW[73728+o+1];
    }
    #pragma unroll
    for (int off = 32; off > 0; off >>= 1) {
        a0 += __shfl_down(a0, off, 64);
        a1 += __shfl_down(a1, off, 64);
        a2 += __shfl_down(a2, off, 64);
        a3 += __shfl_down(a3, off, 64);
    }
    __shared__ float red[4][4];
    const int wave = tid >> 6, lane = tid & 63;
    if (lane == 0) { red[0][wave]=a0; red[1][wave]=a1; red[2][wave]=a2; red[3][wave]=a3; }
    __syncthreads();
    if (tid < 4) {
        float s = red[tid][0]+red[tid][1]+red[tid][2]+red[tid][3] + lb[tid];
        out[b*4 + tid] = sigm(s);
    }
}

extern "C" void kernel_launch(void* const* d_in, const int* in_sizes, int n_in,
                              void* d_out, int out_size, void* d_ws, size_t ws_size,
                              hipStream_t stream) {
    const float* x   = (const float*)d_in[0];
    const float* ea  = (const float*)d_in[1];
    const float* cW  = (const float*)d_in[2];
    const float* cb  = (const float*)d_in[3];
    const float* gam = (const float*)d_in[4];
    const float* bet = (const float*)d_in[5];
    const float* Wih = (const float*)d_in[6];
    const float* Whh = (const float*)d_in[7];
    const float* bih = (const float*)d_in[8];
    const float* bhh = (const float*)d_in[9];
    const float* lW  = (const float*)d_in[10];
    const float* lb  = (const float*)d_in[11];
    const int*   ei  = (const int*)d_in[12];
    float* out = (float*)d_out;

    // Workspace (~72 MB):
    // [bn_acc 40KB][Wp 2.75MB][X 15.7MB][big 53.6MB]
    // big phase 1: y_pre @0 (31.5MB)
    // big phase 2: cnt @0 (128KB region; 48x8 counters, 128B-padded),
    //              c @128KB (2MB), h_all @128KB+2MB (49 x 1MB)
    char* ws = (char*)d_ws;
    float* bn_acc = (float*)ws;
    bf16*  Wp     = (bf16*)(ws + 40960);
    bf16*  X      = (bf16*)(ws + 2793472);
    char*  big    = ws + 18522112;
    float* y_pre  = (float*)big;
    int*   cnt    = (int*)big;
    float* c_buf  = (float*)(big + 131072);
    bf16*  h_all  = (bf16*)(big + 131072 + 2097152);

    (void)hipFuncSetAttribute((const void*)k_lstm,
                              hipFuncAttributeMaxDynamicSharedMemorySize, 131072);

    static int nblk = 0;                 // persistent grid: 1 block/CU (128KB LDS)
    if (nblk == 0) {
        int dev = 0, ncu = 0;
        if (hipGetDevice(&dev) != hipSuccess) dev = 0;
        if (hipDeviceGetAttribute(&ncu, hipDeviceAttributeMultiprocessorCount, dev)
                != hipSuccess || ncu <= 0) ncu = 256;
        nblk = ncu; if (nblk > 256) nblk = 256;
        nblk = (nblk/32)*32; if (nblk < 32) nblk = 32;  // keep ui invariant per block
    }

    k_pack<<<5376, 256, 0, stream>>>(Wih, Whh, Wp, bn_acc);
    k_graph<<<NG_/4, 256, 0, stream>>>(x, ea, cW, cb, ei, y_pre, bn_acc);
    k_bn<<<NF_/256, 256, 0, stream>>>(y_pre, bn_acc, gam, bet, X);
    // zero cnt (128KB) + c (2MB) + h_all slab 0 (1MB) = 204800 float4
    k_zero<<<800, 256, 0, stream>>>((float4*)big, 204800);
    k_lstm<<<nblk, 512, 131072, stream>>>(X, Wp, bih, bhh, h_all, c_buf, cnt);
    k_final<<<B_, 256, 0, stream>>>(h_all + (size_t)B_*H_, lW, lb, out);
}

// Round 7
// 713.452 us; speedup vs baseline: 1.5188x; 1.0194x over previous
//
#include <hip/hip_runtime.h>
#include <hip/hip_bf16.h>

// ECLGCNN: ChebConv(K=3) on 49152 disjoint 32-node graphs -> per-sample BN ->
// sigmoid -> LSTM(48 steps, H=512) -> linear head. Inputs fp32, output fp32.
// R14: kill the flag-line RMW serialization. R13 pinned at 8.3us/step; ~2us of
// that is 32 producers fetch_add-ing ONE line (MALL line-RMWs ~70ns each,
// last producer queues ~32 deep). Now: one flag per (t,mi,ui) on its OWN 128B
// line (stores parallelize at MALL), producer does a single relaxed agent
// STORE; consumer polls with wave0 lanes 0-15 (distinct lines, sleep(4)).
// Split waits: P1 waits only ui<16 producers; ui>=16 poll overlaps h-lo
// staging issue. Everything else identical to R13 (W1/W2-resident, 128KB LDS).

#define B_    1024
#define T_    48
#define NPG_  32
#define F_    5
#define H_    512
#define EPG_  256
#define NG_   (B_*T_)          // 49152 graphs
#define N_    (B_*T_*NPG_)     // 1572864 nodes
#define E_    (B_*T_*EPG_)     // 12582912 edges
#define NF_   (N_*F_)          // 7864320

typedef __bf16 bf16x8 __attribute__((ext_vector_type(8)));
typedef float  f32x4  __attribute__((ext_vector_type(4)));
typedef __hip_bfloat16 bf16;

__device__ __forceinline__ float sigm(float x)   { return 1.0f/(1.0f+__expf(-x)); }
__device__ __forceinline__ float tanh_f(float x) { return 2.0f/(1.0f+__expf(-2.0f*x)) - 1.0f; }

__device__ __forceinline__ void gl_lds16(const void* g, void* l) {
    __builtin_amdgcn_global_load_lds((const __attribute__((address_space(1))) unsigned int*)g,
                                     (__attribute__((address_space(3))) unsigned int*)l, 16, 0, 0);
}

// write-through bf16 store: coherent at agent scope (MALL), no local-L2 dirty line
__device__ __forceinline__ void store_h_wt(bf16* p, float v) {
    bf16 b = __float2bfloat16(v);
    unsigned short us; __builtin_memcpy(&us, &b, 2);
    __hip_atomic_store(reinterpret_cast<unsigned short*>(p), us,
                       __ATOMIC_RELAXED, __HIP_MEMORY_SCOPE_AGENT);
}

__global__ __launch_bounds__(256) void k_zero(float4* p, int n) {
    int i = blockIdx.x*256 + threadIdx.x;
    if (i < n) p[i] = make_float4(0.f, 0.f, 0.f, 0.f);
}

// Pack W' = [Wih | Whh] row-major [2048][672], fp32 -> bf16. Blocks 0-9 also
// zero bn_acc (k_graph atomic-accumulates BN partials into it).
__global__ __launch_bounds__(256) void k_pack(const float* __restrict__ Wih,
                                              const float* __restrict__ Whh,
                                              bf16* __restrict__ Wp,
                                              float* __restrict__ bn_acc) {
    int i = blockIdx.x*256 + threadIdx.x;           // < 2048*672
    if (blockIdx.x < 10) bn_acc[blockIdx.x*256 + threadIdx.x] = 0.f;
    int r = i / 672, c = i - r*672;
    float v = (c < 160) ? Wih[r*160 + c] : Whh[r*512 + (c-160)];
    Wp[i] = __float2bfloat16(v);
}

// Graph-per-wave ChebConv: 4 graphs per 256-thread block.
__global__ __launch_bounds__(256) void k_graph(
    const float* __restrict__ x, const float* __restrict__ ea,
    const float* __restrict__ cW, const float* __restrict__ cb,
    const int* __restrict__ ei, float* __restrict__ y_pre,
    float* __restrict__ bn_acc)
{
    const int tid = threadIdx.x, w = tid >> 6, lane = tid & 63;
    const int g = blockIdx.x*4 + w;
    __shared__ float Msh[4][1056];                  // Mt[d][s], row stride 33
    __shared__ float dinv[4][32];
    __shared__ float T0s[4][160], T1s[4][160], T2s[4][160];
    __shared__ __align__(16) float Spad[4][256];    // scaled vec, rows padded to 8
    __shared__ float Wsh[75], bsh[5];
    float* mt = Msh[w];

    if (lane < 75) Wsh[lane] = cW[lane];
    if (lane < 5)  bsh[lane] = cb[lane];
    const float4 ew = *reinterpret_cast<const float4*>(ea + (size_t)g*256 + lane*4);
    const int4   es = *reinterpret_cast<const int4*>(ei + (size_t)g*256 + lane*4);
    const int4   ed = *reinterpret_cast<const int4*>(ei + (size_t)E_ + (size_t)g*256 + lane*4);
    T0s[w][lane]      = x[(size_t)g*160 + lane];
    T0s[w][64+lane]   = x[(size_t)g*160 + 64 + lane];
    if (lane < 32) T0s[w][128+lane] = x[(size_t)g*160 + 128 + lane];
    for (int i = lane; i < 1056; i += 64) mt[i] = 0.f;
    __syncthreads();
    atomicAdd(&mt[(ed.x & 31)*33 + (es.x & 31)], ew.x);
    atomicAdd(&mt[(ed.y & 31)*33 + (es.y & 31)], ew.y);
    atomicAdd(&mt[(ed.z & 31)*33 + (es.z & 31)], ew.z);
    atomicAdd(&mt[(ed.w & 31)*33 + (es.w & 31)], ew.w);
    __syncthreads();
    {                                               // deg[s] = sum_d Mt[d][s], 64-lane
        const int s = lane & 31, hh = lane >> 5;
        float dg = 0.f;
        #pragma unroll
        for (int k = 0; k < 16; ++k) dg += mt[(hh*16 + k)*33 + s];
        dg += __shfl_xor(dg, 32, 64);
        if (lane < 32) dinv[w][lane] = dg > 0.f ? rsqrtf(dg) : 0.f;
    }
    __syncthreads();
    for (int i = lane; i < 160; i += 64) Spad[w][(i/5)*8 + (i%5)] = dinv[w][i/5]*T0s[w][i];
    __syncthreads();
    {                                               // T1 = -dinv .* (Mt @ S0), 64-lane
        const int d = lane & 31, hh = lane >> 5;
        float a0=0.f,a1=0.f,a2=0.f,a3=0.f,a4=0.f;
        #pragma unroll 4
        for (int s2 = 0; s2 < 16; ++s2) {
            const int s = s2*2 + hh;
            const float m = mt[d*33+s];
            const float4 sv = *reinterpret_cast<const float4*>(&Spad[w][s*8]);
            const float s4 = Spad[w][s*8+4];
            a0 += m*sv.x; a1 += m*sv.y; a2 += m*sv.z; a3 += m*sv.w; a4 += m*s4;
        }
        a0 += __shfl_xor(a0, 32, 64); a1 += __shfl_xor(a1, 32, 64);
        a2 += __shfl_xor(a2, 32, 64); a3 += __shfl_xor(a3, 32, 64);
        a4 += __shfl_xor(a4, 32, 64);
        if (lane < 32) {
            const float sc = -dinv[w][d];
            T1s[w][d*5+0]=sc*a0; T1s[w][d*5+1]=sc*a1; T1s[w][d*5+2]=sc*a2;
            T1s[w][d*5+3]=sc*a3; T1s[w][d*5+4]=sc*a4;
        }
    }
    __syncthreads();
    for (int i = lane; i < 160; i += 64) Spad[w][(i/5)*8 + (i%5)] = dinv[w][i/5]*T1s[w][i];
    __syncthreads();
    {                                               // T2 = 2 L~ T1 - T0, 64-lane
        const int d = lane & 31, hh = lane >> 5;
        float a0=0.f,a1=0.f,a2=0.f,a3=0.f,a4=0.f;
        #pragma unroll 4
        for (int s2 = 0; s2 < 16; ++s2) {
            const int s = s2*2 + hh;
            const float m = mt[d*33+s];
            const float4 sv = *reinterpret_cast<const float4*>(&Spad[w][s*8]);
            const float s4 = Spad[w][s*8+4];
            a0 += m*sv.x; a1 += m*sv.y; a2 += m*sv.z; a3 += m*sv.w; a4 += m*s4;
        }
        a0 += __shfl_xor(a0, 32, 64); a1 += __shfl_xor(a1, 32, 64);
        a2 += __shfl_xor(a2, 32, 64); a3 += __shfl_xor(a3, 32, 64);
        a4 += __shfl_xor(a4, 32, 64);
        if (lane < 32) {
            const float sc = -2.f*dinv[w][d];
            T2s[w][d*5+0]=sc*a0-T0s[w][d*5+0]; T2s[w][d*5+1]=sc*a1-T0s[w][d*5+1];
            T2s[w][d*5+2]=sc*a2-T0s[w][d*5+2]; T2s[w][d*5+3]=sc*a3-T0s[w][d*5+3];
            T2s[w][d*5+4]=sc*a4-T0s[w][d*5+4];
        }
    }
    __syncthreads();
    float* vb = mt;                                 // reuse adjacency LDS for y
    for (int i = lane; i < 160; i += 64) {
        const int n = i/5, f = i - 5*n;
        float v = bsh[f];
        #pragma unroll
        for (int c = 0; c < 5; ++c)
            v += T0s[w][n*5+c]*Wsh[c*5+f] + T1s[w][n*5+c]*Wsh[25+c*5+f] + T2s[w][n*5+c]*Wsh[50+c*5+f];
        y_pre[(size_t)g*160 + i] = v;
        vb[i] = v;
    }
    __syncthreads();
    {                                               // BN partials -> bn_acc (atomic)
        const int f = lane % 5, cs = (lane/5) & 3;
        const bool sq = lane >= 20;
        float sm = 0.f;
        if (lane < 40) {
            #pragma unroll
            for (int k = 0; k < 8; ++k) { float v = vb[(cs*8+k)*5+f]; sm += sq ? v*v : v; }
        }
        sm += __shfl_down(sm, 5, 64);
        sm += __shfl_down(sm, 10, 64);
        if (lane < 40 && cs == 0)
            atomicAdd(&bn_acc[(size_t)(g/T_)*10 + f + (sq?5:0)], sm);
    }
}

__global__ __launch_bounds__(256) void k_bn(
    const float* __restrict__ y_pre, const float* __restrict__ bn_acc,
    const float* __restrict__ gamma, const float* __restrict__ beta,
    bf16* __restrict__ X)
{
    const int i = blockIdx.x*256 + threadIdx.x;
    const int b   = i / 7680;
    const int rem = i - b*7680;
    const int t   = rem / 160;
    const int pf  = rem - t*160;
    const int f   = pf % 5;
    const float inv  = 1.0f/1536.0f;
    const float mean = bn_acc[b*10+f]*inv;
    const float var  = bn_acc[b*10+5+f]*inv - mean*mean;
    const float v = gamma[f]*(y_pre[i]-mean)*rsqrtf(var+1e-5f) + beta[f];
    X[((size_t)t*B_ + b)*160 + pf] = __float2bfloat16(sigm(v));
}

// ---- W-resident persistent LSTM (128KB LDS, per-producer flag lines) ----
// 256 tiles (8 m-groups x 32 u-tiles), tile = 128 batch rows x 64 gate rows
// (16u x 4 gates). 512-thread blocks (8 waves), 1 block/CU. LDS 131072:
//   A-buf 64KB  (P0: X 40KB + W0 20KB staged per step; P1/P2: h halves 64KB)
//   W1 32KB / W2 32KB -- staged ONCE before the t loop (h-part weights).
// Flags: flag[t][mi][ui] on its own 128B line; producer = 1 relaxed agent
// STORE after vmcnt drain (parallel at MALL, no RMW queueing); consumer =
// wave0 lanes 0-15 poll distinct lines + s_sleep(4). P1 waits ui<16 only
// (poll after P0 mfma); ui>=16 poll overlaps h-lo staging issue.

__device__ __forceinline__ void stage_A512(const char* gbase, int strideB, char* lds,
                                           int gpr, int xmask, int nper, int tid) {
    for (int p = 0; p < nper; ++p) {
        const int S = p*512 + tid;
        const int row = S / gpr;
        const int col = (S - row*gpr) ^ (row & xmask);
        gl_lds16(gbase + (size_t)row*strideB + (size_t)col*16, lds + (size_t)S*16);
    }
}

__device__ __forceinline__ void stage_W512(const char* Wbase, char* lds,
                                           int gpr, int xmask, int ntot, int tid, int u0) {
    for (int p = 0; p*512 < ntot; ++p) {
        const int S = p*512 + tid;
        if (S < ntot) {
            const int row = S / gpr;
            const int col = (S - row*gpr) ^ (row & xmask);
            const int wrow = ((row >> 4) << 9) + u0 + (row & 15);
            gl_lds16(Wbase + (size_t)wrow*1344 + (size_t)col*16, lds + (size_t)S*16);
        }
    }
}

__device__ __forceinline__ void mfma_phase(const char* Al, const char* Wl, int gpr,
                                           int xmask, int nkk, int arow, int lo,
                                           int quad, f32x4 acc[4]) {
    for (int kk = 0; kk < nkk; ++kk) {
        const int kq = kk*4 + quad;
        const bf16x8 a = *reinterpret_cast<const bf16x8*>(
            Al + ((size_t)arow*gpr + (kq ^ (arow & xmask)))*16);
        #pragma unroll
        for (int g = 0; g < 4; ++g) {
            const int wr = g*16 + lo;
            const bf16x8 b = *reinterpret_cast<const bf16x8*>(
                Wl + ((size_t)wr*gpr + (kq ^ (wr & xmask)))*16);
            acc[g] = __builtin_amdgcn_mfma_f32_16x16x32_bf16(a, b, acc[g], 0, 0, 0);
        }
    }
}

// poll 16 flags (one per lane, distinct 128B lines)
__device__ __forceinline__ void poll16(const int* base, int lane) {
    const int* p = base + (size_t)lane*32;
    while (__hip_atomic_load(p, __ATOMIC_RELAXED, __HIP_MEMORY_SCOPE_AGENT) == 0)
        __builtin_amdgcn_s_sleep(4);
}

__global__ __launch_bounds__(512, 1) void k_lstm(
    const bf16* __restrict__ X,  const bf16* __restrict__ Wp,
    const float* __restrict__ bih, const float* __restrict__ bhh,
    bf16* __restrict__ h_all, float* __restrict__ c_buf,
    int* __restrict__ cnt)
{
    extern __shared__ char sm[];
    char* Al  = sm;                 // 65536 (P0: X@0 40960 + W0@40960 20480)
    char* W1l = sm + 65536;         // 32768
    char* W2l = sm + 98304;         // 32768
    const int tid = threadIdx.x;
    const int lane = tid & 63, w = tid >> 6;
    const int lo = lane & 15, quad = lane >> 4;
    const int arow = w*16 + lo;     // A row within 128-row tile
    const char* Wb = (const char*)Wp;
    const int ui = blockIdx.x & 31;
    const int u0 = ui*16;

    // stage resident W1/W2 once (depend only on ui, invariant per block)
    stage_W512(Wb + 320, W1l, 32, 7, 2048, tid, u0);
    stage_W512(Wb + 832, W2l, 32, 7, 2048, tid, u0);
    const int u = u0 + lo;
    const float bI = bih[u]      + bhh[u];
    const float bF = bih[512+u]  + bhh[512+u];
    const float bG = bih[1024+u] + bhh[1024+u];
    const float bO = bih[1536+u] + bhh[1536+u];

    for (int t = 0; t < T_; ++t) {
        const char* Hin = (const char*)(h_all + (size_t)t*B_*H_);
        bf16* h_out = h_all + (size_t)(t+1)*B_*H_;
        for (int tile = blockIdx.x; tile < 256; tile += gridDim.x) {
            const int mi = tile >> 5;
            const int m0 = mi*128;
            const char* Xb = (const char*)X + (size_t)t*B_*320 + (size_t)m0*320;
            const char* Hb = Hin + (size_t)m0*1024;
            const int* fprev = cnt + (size_t)((t-1)*8 + mi)*32*32;
            f32x4 acc[4] = {};

            // phase 0: X part (K=160) -- h-independent
            stage_A512(Xb, 320, Al, 20, 3, 5, tid);          // X tile 40KB
            stage_W512(Wb, Al + 40960, 20, 3, 1280, tid, u0); // W0 20KB (L2-hot)
            __syncthreads();                          // drains vmcnt: LDS ready
            mfma_phase(Al, Al + 40960, 20, 3, 5, arow, lo, quad, acc);
            if (t > 0 && w == 0 && lane < 16)         // wait lo producers (ui<16)
                poll16(fprev, lane);
            __syncthreads();
            // phase 1: h[0:256) -- needs lo producers only
            stage_A512(Hb, 1024, Al, 32, 7, 8, tid);
            if (t > 0 && w == 0 && lane < 16)         // hi poll overlaps staging
                poll16(fprev + 16*32, lane);
            __syncthreads();                          // drains vmcnt + joins poll
            mfma_phase(Al, W1l, 32, 7, 8, arow, lo, quad, acc);
            __syncthreads();
            // phase 2: h[256:512) -- hi producers confirmed above
            stage_A512(Hb + 512, 1024, Al, 32, 7, 8, tid);
            __syncthreads();
            mfma_phase(Al, W2l, 32, 7, 8, arow, lo, quad, acc);

            #pragma unroll
            for (int r = 0; r < 4; ++r) {
                const int m = m0 + w*16 + quad*4 + r;
                const int idx = m*512 + u;
                const float iv = acc[0][r] + bI;
                const float fv = acc[1][r] + bF;
                const float gv = acc[2][r] + bG;
                const float ov = acc[3][r] + bO;
                const float c_new = sigm(fv)*c_buf[idx] + sigm(iv)*tanh_f(gv);
                c_buf[idx] = c_new;
                store_h_wt(&h_out[idx], sigm(ov)*tanh_f(c_new));
            }
            __syncthreads();                          // drains vmcnt: h at MALL
            if (tid == 0)                             // own line: parallel at MALL
                __hip_atomic_store(cnt + (size_t)((t*8 + mi)*32 + ui)*32, 1,
                                   __ATOMIC_RELAXED, __HIP_MEMORY_SCOPE_AGENT);
        }
    }
}

// out[b,j] = sigmoid( sum_{t,u} sigm(h[t,b,u]) * lin_W[j, t*512+u] + lin_b[j] )
__global__ __launch_bounds__(256) void k_final(
    const bf16* __restrict__ hs, const float* __restrict__ lW,
    const float* __restrict__ lb, float* __restrict__ out)
{
    const int b = blockIdx.x, tid = threadIdx.x;
    const int u = tid*2;
    float a0=0.f, a1=0.f, a2=0.f, a3=0.f;
    for (int t = 0; t < T_; ++t) {
        const bf16* hr = hs + ((size_t)t*B_ + b)*H_ + u;
        const float h0 = sigm((float)hr[0]), h1 = sigm((float)hr[1]);
        const int o = t*H_ + u;
        a0 += h0*lW[o]         + h1*lW[o+1];
        a1 += h0*lW[24576+o]   + h1*lW[24576+o+1];
        a2 += h0*lW[49152+o]   + h1*lW[49152+o+1];
        a3 += h0*lW[73728+o]   + h1*lW[73728+o+1];
    }
    #pragma unroll
    for (int off = 32; off > 0; off >>= 1) {
        a0 += __shfl_down(a0, off, 64);
        a1 += __shfl_down(a1, off, 64);
        a2 += __shfl_down(a2, off, 64);
        a3 += __shfl_down(a3, off, 64);
    }
    __shared__ float red[4][4];
    const int wave = tid >> 6, lane = tid & 63;
    if (lane == 0) { red[0][wave]=a0; red[1][wave]=a1; red[2][wave]=a2; red[3][wave]=a3; }
    __syncthreads();
    if (tid < 4) {
        float s = red[tid][0]+red[tid][1]+red[tid][2]+red[tid][3] + lb[tid];
        out[b*4 + tid] = sigm(s);
    }
}

extern "C" void kernel_launch(void* const* d_in, const int* in_sizes, int n_in,
                              void* d_out, int out_size, void* d_ws, size_t ws_size,
                              hipStream_t stream) {
    const float* x   = (const float*)d_in[0];
    const float* ea  = (const float*)d_in[1];
    const float* cW  = (const float*)d_in[2];
    const float* cb  = (const float*)d_in[3];
    const float* gam = (const float*)d_in[4];
    const float* bet = (const float*)d_in[5];
    const float* Wih = (const float*)d_in[6];
    const float* Whh = (const float*)d_in[7];
    const float* bih = (const float*)d_in[8];
    const float* bhh = (const float*)d_in[9];
    const float* lW  = (const float*)d_in[10];
    const float* lb  = (const float*)d_in[11];
    const int*   ei  = (const int*)d_in[12];
    float* out = (float*)d_out;

    // Workspace (~70.2 MB):
    // [bn_acc 40KB][Wp 2.75MB][X 15.7MB][big 52.5MB]
    // big phase 1: y_pre @0 (31.5MB)
    // big phase 2: flags @0 (1.5MB: 48x8x32 x 128B lines),
    //              c @1.5MB (2MB), h_all @3.5MB (49 x 1MB)
    char* ws = (char*)d_ws;
    float* bn_acc = (float*)ws;
    bf16*  Wp     = (bf16*)(ws + 40960);
    bf16*  X      = (bf16*)(ws + 2793472);
    char*  big    = ws + 18522112;
    float* y_pre  = (float*)big;
    int*   cnt    = (int*)big;
    float* c_buf  = (float*)(big + 1572864);
    bf16*  h_all  = (bf16*)(big + 1572864 + 2097152);

    (void)hipFuncSetAttribute((const void*)k_lstm,
                              hipFuncAttributeMaxDynamicSharedMemorySize, 131072);

    static int nblk = 0;                 // persistent grid: 1 block/CU (128KB LDS)
    if (nblk == 0) {
        int dev = 0, ncu = 0;
        if (hipGetDevice(&dev) != hipSuccess) dev = 0;
        if (hipDeviceGetAttribute(&ncu, hipDeviceAttributeMultiprocessorCount, dev)
                != hipSuccess || ncu <= 0) ncu = 256;
        nblk = ncu; if (nblk > 256) nblk = 256;
        nblk = (nblk/32)*32; if (nblk < 32) nblk = 32;  // keep ui invariant per block
    }

    k_pack<<<5376, 256, 0, stream>>>(Wih, Whh, Wp, bn_acc);
    k_graph<<<NG_/4, 256, 0, stream>>>(x, ea, cW, cb, ei, y_pre, bn_acc);
    k_bn<<<NF_/256, 256, 0, stream>>>(y_pre, bn_acc, gam, bet, X);
    // zero flags (1.5MB) + c (2MB) + h_all slab 0 (1MB) = 294912 float4
    k_zero<<<1152, 256, 0, stream>>>((float4*)big, 294912);
    k_lstm<<<nblk, 512, 131072, stream>>>(X, Wp, bih, bhh, h_all, c_buf, cnt);
    k_final<<<B_, 256, 0, stream>>>(h_all + (size_t)B_*H_, lW, lb, out);
}